// Round 14
// baseline (2575.981 us; speedup 1.0000x reference)
//
#include <hip/hip_runtime.h>
#include <hip/hip_bf16.h>

#define B_ 1024
#define T_ 128
#define E_ 128
#define U_ 512
#define V_ 32000
#define NC 16   // col chunks (blocks per group)
#define NG 16   // row groups
#define MB 64   // rows per group
#define NB 32   // cols per chunk
#define HS ((size_t)B_ * U_)

#define CTR_OFF 0
#define XMASK_OFF (512u << 10)
#define FH0_OFF (520u << 10)
#define FH1_OFF (528u << 10)
#define H0H_OFF (1u << 20)   // 3 buffers x 1 MB
#define H0L_OFF (4u << 20)   // 3 buffers x 1 MB
#define H1H_OFF (7u << 20)   // 2 buffers x 1 MB
#define H1L_OFF (9u << 20)   // 2 buffers x 1 MB
#define EMBW_OFF (11u << 20)
#define ZERO_BYTES (11u << 20)

typedef unsigned int uint32;
typedef __bf16 bf16x8 __attribute__((ext_vector_type(8)));
typedef float f32x4 __attribute__((ext_vector_type(4)));
typedef unsigned short us8 __attribute__((ext_vector_type(8)));

#define MFMA __builtin_amdgcn_mfma_f32_16x16x32_bf16

__device__ __forceinline__ unsigned short f2b(float f) {
  uint32 u = __builtin_bit_cast(uint32, f);
  u += 0x7fffu + ((u >> 16) & 1u);   // RNE
  return (unsigned short)(u >> 16);
}
__device__ __forceinline__ float b2f(unsigned short h) {
  return __builtin_bit_cast(float, (uint32)h << 16);
}

// Swizzled LDS fragment read: row-major [row][K] bf16, byte ^= (row&7)<<4
__device__ __forceinline__ bf16x8 lds_frag(const unsigned short* s, int row, int k, int K) {
  uint32 off = (uint32)((row * K + k) * 2) ^ (uint32)((row & 7) << 4);
  us8 v = *(const us8*)((const char*)s + off);
  return __builtin_bit_cast(bf16x8, v);
}
__device__ __forceinline__ bf16x8 g_frag(const unsigned short* p) {
  us8 v = *(const us8*)p;
  return __builtin_bit_cast(bf16x8, v);
}
__device__ __forceinline__ void st_coh(unsigned short* p, unsigned short v) {
  __hip_atomic_store(p, v, __ATOMIC_RELAXED, __HIP_MEMORY_SCOPE_AGENT);
}
template <bool FAST>
__device__ __forceinline__ void st_h(unsigned short* p, unsigned short v) {
  if (FAST) *p = v; else st_coh(p, v);
}

// Per-wave release (r9-PROVEN): drain own h stores, lane 0 publishes flag.
template <bool FAST>
__device__ __forceinline__ void wave_signal(uint32* f, uint32 val, int lane) {
  asm volatile("s_waitcnt vmcnt(0)" ::: "memory");
  if (lane == 0) {
    if (FAST) *(volatile uint32*)f = val;  // write-through to local L2
    else __hip_atomic_store(f, val, __ATOMIC_RELAXED, __HIP_MEMORY_SCOPE_AGENT);
  }
}

// Per-wave wait (r9-PROVEN): lanes 0-15 poll flagH0 >= t; lanes 16-31 poll
// flagH1 >= t-DLT. FAST: plain volatile loads + L1 buffer_inv per retry
// (NEVER hand-rolled sc0 loads — those deadlock: r8/r10/r11/r12).
template <bool FAST, int DLT>
__device__ __forceinline__ void wave_wait(const uint32* f0, const uint32* f1,
                                          int t, int lane) {
  if (t == 0) return;
  const int t1 = t - DLT;
  const uint32 tgt = (lane < 16) ? (uint32)t
                                 : ((lane < 32 && t1 > 0) ? (uint32)t1 : 0u);
  const uint32* p = (lane < 16) ? (f0 + lane)
                                : ((lane < 32) ? (f1 + (lane & 15)) : f0);
  while (true) {
    uint32 v;
    if (FAST) v = *(const volatile uint32*)p;
    else v = __hip_atomic_load(p, __ATOMIC_RELAXED, __HIP_MEMORY_SCOPE_AGENT);
    if (__all(v >= tgt)) break;
    if (FAST) asm volatile("buffer_inv" ::: "memory");
    __builtin_amdgcn_s_sleep(2);
  }
  if (FAST) asm volatile("buffer_inv\n\ts_waitcnt vmcnt(0)" ::: "memory");
  else __builtin_amdgcn_fence(__ATOMIC_ACQUIRE, "agent");
}

// Block-level group barrier (used ONCE for the XCD co-residency check).
__device__ __forceinline__ void bar_agent(uint32* ctr, int phase, int g, int tid) {
  asm volatile("s_waitcnt vmcnt(0)" ::: "memory");
  __syncthreads();
  if (tid == 0) {
    uint32* a = &ctr[(uint32)((phase << 4) | g) << 4];
    __hip_atomic_fetch_add(a, 1u, __ATOMIC_RELAXED, __HIP_MEMORY_SCOPE_AGENT);
    while (__hip_atomic_load(a, __ATOMIC_RELAXED, __HIP_MEMORY_SCOPE_AGENT) < NC)
      __builtin_amdgcn_s_sleep(1);
    __builtin_amdgcn_fence(__ATOMIC_ACQUIRE, "agent");
  }
  __syncthreads();
}

__global__ void rnn_init(unsigned char* ws) {
  const uint4 z = {0u, 0u, 0u, 0u};
  uint4* p = (uint4*)ws;
  size_t n = ZERO_BYTES / 16;
  for (size_t j = (size_t)blockIdx.x * blockDim.x + threadIdx.x; j < n;
       j += (size_t)gridDim.x * blockDim.x)
    p[j] = z;
}

// embW[v][u] = sum_e emb[v][e] * Wx0[e][u], stored bf16. grid (V/64, U/64).
__global__ __launch_bounds__(256) void embw_gemm(const float* __restrict__ emb,
                                                 const float* __restrict__ Wx0,
                                                 unsigned short* __restrict__ embW) {
  const int tid = threadIdx.x;
  const int lane = tid & 63;
  const int wv = tid >> 6;
  const int arow = lane & 15;
  const int kgrp = (lane >> 4) * 8;
  const int vrow = blockIdx.x * 64 + wv * 16;

  bf16x8 a[4];
  for (int kt = 0; kt < 4; ++kt) {
    const float* p = emb + (size_t)(vrow + arow) * E_ + kt * 32 + kgrp;
    float4 f0 = ((const float4*)p)[0];
    float4 f1 = ((const float4*)p)[1];
    us8 u;
    u[0] = f2b(f0.x); u[1] = f2b(f0.y); u[2] = f2b(f0.z); u[3] = f2b(f0.w);
    u[4] = f2b(f1.x); u[5] = f2b(f1.y); u[6] = f2b(f1.z); u[7] = f2b(f1.w);
    a[kt] = __builtin_bit_cast(bf16x8, u);
  }
  const int c0 = blockIdx.y * 64;
  for (int nt = 0; nt < 4; ++nt) {
    const int col = c0 + nt * 16 + (lane & 15);
    f32x4 acc = {0.f, 0.f, 0.f, 0.f};
    for (int kt = 0; kt < 4; ++kt) {
      us8 ub;
      for (int j = 0; j < 8; ++j)
        ub[j] = f2b(Wx0[(size_t)(kt * 32 + kgrp + j) * U_ + col]);
      acc = MFMA(a[kt], __builtin_bit_cast(bf16x8, ub), acc, 0, 0, 0);
    }
    const int crow = vrow + (lane >> 4) * 4;
    for (int i = 0; i < 4; ++i)
      embW[(size_t)(crow + i) * U_ + col] = f2b(acc[i]);
  }
}

// ---- Layer-0 role wave: h0'(t) = tanh(embW + h0'(t-1)@Wh0 + b0), t=0..T-1.
template <bool FAST>
__device__ __forceinline__ void l0_loop(
    const int* __restrict__ tokens, const unsigned short* __restrict__ embW,
    unsigned short* h0h, unsigned short* h0l, const uint32* f0w,
    const uint32* f1w, uint32* myF0, const unsigned short* sWh0h,
    const unsigned short* sWh0l, int r0, int c0, int lane, int rowB, int kgrp,
    int rowA, float b0v0, float b0v1) {
  const int l15 = lane & 15;
  const float b0a[2] = {b0v0, b0v1};
  unsigned short embP[2][4];
#pragma unroll
  for (int nt = 0; nt < 2; ++nt)
    for (int i = 0; i < 4; ++i) {
      int tk = tokens[(size_t)(r0 + rowB + i) * T_ + 0];
      embP[nt][i] = embW[(size_t)tk * U_ + c0 + nt * 16 + l15];
    }

  for (int t = 0; t < T_; ++t) {
    wave_wait<FAST, 2>(f0w, f1w, t, lane);  // h0'(t-1) ready + 3-buf safety

    const size_t rb = (size_t)((t + 2) % 3) * HS;  // h0'(t-1)
    bf16x8 hh[16], hl[16];
    {
      const unsigned short* ph = h0h + rb + (size_t)rowA * U_ + kgrp;
      const unsigned short* pl = h0l + rb + (size_t)rowA * U_ + kgrp;
#pragma unroll
      for (int kt = 0; kt < 16; ++kt) {
        hh[kt] = g_frag(ph + kt * 32);
        hl[kt] = g_frag(pl + kt * 32);
      }
    }
    const size_t wb = (size_t)(t % 3) * HS;
#pragma unroll
    for (int nt = 0; nt < 2; ++nt) {
      const int colL = nt * 16 + l15;
      f32x4 aC, aD = {0.f, 0.f, 0.f, 0.f};
      for (int i = 0; i < 4; ++i) aC[i] = b0a[nt] + b2f(embP[nt][i]);
#pragma unroll
      for (int kt = 0; kt < 16; ++kt) {
        bf16x8 bh = lds_frag(sWh0h, colL, kt * 32 + kgrp, U_);
        bf16x8 bl = lds_frag(sWh0l, colL, kt * 32 + kgrp, U_);
        aC = MFMA(hh[kt], bh, aC, 0, 0, 0);
        aD = MFMA(hl[kt], bh, aD, 0, 0, 0);
        aD = MFMA(hh[kt], bl, aD, 0, 0, 0);
      }
      size_t ob = wb + (size_t)(r0 + rowB) * U_ + (c0 + colL);
      for (int i = 0; i < 4; ++i) {
        float v = tanhf(aC[i] + aD[i]);
        unsigned short hi = f2b(v);
        st_h<FAST>(&h0h[ob + (size_t)i * U_], hi);
        st_h<FAST>(&h0l[ob + (size_t)i * U_], f2b(v - b2f(hi)));
      }
    }
    wave_signal<FAST>(myF0, (uint32)(t + 1), lane);

    // embW gather for t+1 strictly AFTER the signal (off the release path).
    if (t + 1 < T_) {
#pragma unroll
      for (int nt = 0; nt < 2; ++nt)
        for (int i = 0; i < 4; ++i) {
          int tk = tokens[(size_t)(r0 + rowB + i) * T_ + (t + 1)];
          embP[nt][i] = embW[(size_t)tk * U_ + c0 + nt * 16 + l15];
        }
    }
  }
}

// ---- Layer-1 role wave: h1'(w-1) = tanh(h0'(w-1)@Wx1 + h1'(w-2)@Wh1 + b1),
// w=1..T. Sequential A-batches (a1 then h0) keep peak VGPR bounded.
template <bool FAST>
__device__ __forceinline__ void l1_loop(
    unsigned short* h0h, unsigned short* h0l, unsigned short* h1h,
    unsigned short* h1l, const uint32* f0w, const uint32* f1w, uint32* myF1,
    const unsigned short* sWx1h, const unsigned short* sWh1h,
    const unsigned short* sWh1l, int r0, int c0, int lane, int rowB, int kgrp,
    int rowA, float b1v0, float b1v1) {
  const int l15 = lane & 15;
  const float b1a[2] = {b1v0, b1v1};

  for (int w = 1; w <= T_; ++w) {
    wave_wait<FAST, 1>(f0w, f1w, w, lane);  // h0'(w-1) + h1 dbuf safety

    f32x4 aB[2];
    {
      const size_t rb1 = (size_t)(w & 1) * HS;  // h1'(w-2)
      bf16x8 ah[16], al[16];
      const unsigned short* p1h = h1h + rb1 + (size_t)rowA * U_ + kgrp;
      const unsigned short* p1l = h1l + rb1 + (size_t)rowA * U_ + kgrp;
#pragma unroll
      for (int kt = 0; kt < 16; ++kt) {
        ah[kt] = g_frag(p1h + kt * 32);
        al[kt] = g_frag(p1l + kt * 32);
      }
#pragma unroll
      for (int nt = 0; nt < 2; ++nt) {
        const int colL = nt * 16 + l15;
        f32x4 acc = {b1a[nt], b1a[nt], b1a[nt], b1a[nt]};
#pragma unroll
        for (int kt = 0; kt < 16; ++kt) {
          bf16x8 bh = lds_frag(sWh1h, colL, kt * 32 + kgrp, U_);
          acc = MFMA(ah[kt], bh, acc, 0, 0, 0);
          acc = MFMA(al[kt], bh, acc, 0, 0, 0);
          if (kt < 15) {
            bf16x8 bl = lds_frag(sWh1l, colL, kt * 32 + kgrp, 480);
            acc = MFMA(ah[kt], bl, acc, 0, 0, 0);
          }
        }
        aB[nt] = acc;
      }
    }
    // h0'(w-1) batch (registers reused from a1)
    const size_t rb0 = (size_t)((w + 2) % 3) * HS;  // (w-1)%3
    bf16x8 hh[16], hl[16];
    {
      const unsigned short* ph = h0h + rb0 + (size_t)rowA * U_ + kgrp;
      const unsigned short* pl = h0l + rb0 + (size_t)rowA * U_ + kgrp;
#pragma unroll
      for (int kt = 0; kt < 16; ++kt) {
        hh[kt] = g_frag(ph + kt * 32);
        hl[kt] = g_frag(pl + kt * 32);
      }
    }
    const size_t wb1 = (size_t)((w - 1) & 1) * HS;
#pragma unroll
    for (int nt = 0; nt < 2; ++nt) {
      const int colL = nt * 16 + l15;
      f32x4 aA = {0.f, 0.f, 0.f, 0.f};
#pragma unroll
      for (int kt = 0; kt < 16; ++kt) {
        bf16x8 bxh = lds_frag(sWx1h, colL, kt * 32 + kgrp, U_);
        aA = MFMA(hh[kt], bxh, aA, 0, 0, 0);
        aA = MFMA(hl[kt], bxh, aA, 0, 0, 0);
      }
      size_t ob = wb1 + (size_t)(r0 + rowB) * U_ + (c0 + colL);
      for (int i = 0; i < 4; ++i) {
        float v = tanhf(aA[i] + aB[nt][i]);
        unsigned short hi = f2b(v);
        st_h<FAST>(&h1h[ob + (size_t)i * U_], hi);
        st_h<FAST>(&h1l[ob + (size_t)i * U_], f2b(v - b2f(hi)));
      }
    }
    wave_signal<FAST>(myF1, (uint32)w, lane);
  }
}

__global__ __launch_bounds__(512, 2) void rnn_main(
    const int* __restrict__ tokens, const float* __restrict__ b0,
    const float* __restrict__ Wh0, const float* __restrict__ Wx1,
    const float* __restrict__ Wh1, const float* __restrict__ b1,
    unsigned char* ws) {
  __shared__ unsigned short sWh0h[NB * U_];   // 32 KB
  __shared__ unsigned short sWh0l[NB * U_];   // 32 KB
  __shared__ unsigned short sWx1h[NB * U_];   // 32 KB
  __shared__ unsigned short sWh1h[NB * U_];   // 32 KB
  __shared__ unsigned short sWh1l[NB * 480];  // 30 KB
  __shared__ uint32 sFast;

  const int tid = threadIdx.x;
  const int bid = blockIdx.x;
  const int g = bid & (NG - 1);
  const int c = bid >> 4;
  const int r0 = g * MB;
  const int c0 = c * NB;

  uint32* ctr = (uint32*)(ws + CTR_OFF);
  uint32* fH0 = (uint32*)(ws + FH0_OFF);
  uint32* fH1 = (uint32*)(ws + FH1_OFF);
  unsigned short* h0h = (unsigned short*)(ws + H0H_OFF);
  unsigned short* h0l = (unsigned short*)(ws + H0L_OFF);
  unsigned short* h1h = (unsigned short*)(ws + H1H_OFF);
  unsigned short* h1l = (unsigned short*)(ws + H1L_OFF);
  const unsigned short* embW = (const unsigned short*)(ws + EMBW_OFF);

  // ---- stage weight slices: f32 global -> bf16 hi(+lo) swizzled LDS ----
  for (int idx = tid; idx < NB * U_; idx += 512) {
    int cl = idx & 31, k = idx >> 5;
    float v = Wh0[(size_t)k * U_ + c0 + cl];
    unsigned short hi = f2b(v);
    uint32 off = (uint32)((cl * U_ + k) * 2) ^ (uint32)((cl & 7) << 4);
    *(unsigned short*)((char*)sWh0h + off) = hi;
    *(unsigned short*)((char*)sWh0l + off) = f2b(v - b2f(hi));
  }
  for (int idx = tid; idx < NB * U_; idx += 512) {
    int cl = idx & 31, k = idx >> 5;
    float v = Wx1[(size_t)k * U_ + c0 + cl];
    uint32 off = (uint32)((cl * U_ + k) * 2) ^ (uint32)((cl & 7) << 4);
    *(unsigned short*)((char*)sWx1h + off) = f2b(v);
  }
  for (int idx = tid; idx < NB * U_; idx += 512) {
    int cl = idx & 31, k = idx >> 5;
    float v = Wh1[(size_t)k * U_ + c0 + cl];
    unsigned short hi = f2b(v);
    uint32 off = (uint32)((cl * U_ + k) * 2) ^ (uint32)((cl & 7) << 4);
    *(unsigned short*)((char*)sWh1h + off) = hi;
    if (k < 480) {
      uint32 offl = (uint32)((cl * 480 + k) * 2) ^ (uint32)((cl & 7) << 4);
      *(unsigned short*)((char*)sWh1l + offl) = f2b(v - b2f(hi));
    }
  }

  // ---- runtime XCD co-residency check (G16: never ASSUME the mapping) ----
  // fetch_or drains before the counter add inside bar_agent -> after the
  // barrier every block reads the same final mask -> group-uniform decision.
  {
    uint32 xcd;
    asm volatile("s_getreg_b32 %0, hwreg(HW_REG_XCC_ID)" : "=s"(xcd));
    uint32* xm = (uint32*)(ws + XMASK_OFF) + (uint32)g * 16;
    if (tid == 0)
      __hip_atomic_fetch_or(xm, 1u << (xcd & 31u), __ATOMIC_RELAXED,
                            __HIP_MEMORY_SCOPE_AGENT);
    bar_agent(ctr, T_, g, tid);
    if (tid == 0) {
      uint32 m = __hip_atomic_load(xm, __ATOMIC_RELAXED, __HIP_MEMORY_SCOPE_AGENT);
      sFast = (__popc(m) == 1) ? 1u : 0u;
    }
  }

  const int lane = tid & 63;
  const int wv = tid >> 6;       // 8 waves
  const int mt = wv & 3;         // M-tile 0..3
  const int role = wv >> 2;      // 0 = layer-0, 1 = layer-1
  const int l15 = lane & 15;
  const int rowB = mt * 16 + ((lane >> 4) << 2);
  const int kgrp = (lane >> 4) * 8;
  const int rowA = r0 + mt * 16 + l15;

  const uint32* f0w = fH0 + (((uint32)g * 4 + mt) << 4);
  const uint32* f1w = fH1 + (((uint32)g * 4 + mt) << 4);
  uint32* myF0 = (uint32*)f0w + c;
  uint32* myF1 = (uint32*)f1w + c;

  __syncthreads();  // weights staged + sFast visible; no block syncs after
  const bool fast = (sFast != 0);

  if (role == 0) {
    const float b0v0 = b0[c0 + l15], b0v1 = b0[c0 + 16 + l15];
    if (fast)
      l0_loop<true>(tokens, embW, h0h, h0l, f0w, f1w, myF0, sWh0h, sWh0l, r0,
                    c0, lane, rowB, kgrp, rowA, b0v0, b0v1);
    else
      l0_loop<false>(tokens, embW, h0h, h0l, f0w, f1w, myF0, sWh0h, sWh0l, r0,
                     c0, lane, rowB, kgrp, rowA, b0v0, b0v1);
  } else {
    const float b1v0 = b1[c0 + l15], b1v1 = b1[c0 + 16 + l15];
    if (fast)
      l1_loop<true>(h0h, h0l, h1h, h1l, f0w, f1w, myF1, sWx1h, sWh1h, sWh1l,
                    r0, c0, lane, rowB, kgrp, rowA, b1v0, b1v1);
    else
      l1_loop<false>(h0h, h0l, h1h, h1l, f0w, f1w, myF1, sWx1h, sWh1h, sWh1l,
                     r0, c0, lane, rowB, kgrp, rowA, b1v0, b1v1);
  }
}

__global__ void rnn_final(const unsigned short* __restrict__ h1h,
                          const unsigned short* __restrict__ h1l,
                          const float* __restrict__ Wo,
                          const float* __restrict__ bo, float* __restrict__ out) {
  int lane = threadIdx.x & 63;
  int b = blockIdx.x * 4 + (threadIdx.x >> 6);
  us8 hh = *(const us8*)(h1h + (size_t)b * U_ + lane * 8);
  us8 hl = *(const us8*)(h1l + (size_t)b * U_ + lane * 8);
  const float4* wp = (const float4*)(Wo + lane * 8);
  float4 w0 = wp[0], w1 = wp[1];
  float s = (b2f(hh[0]) + b2f(hl[0])) * w0.x + (b2f(hh[1]) + b2f(hl[1])) * w0.y +
            (b2f(hh[2]) + b2f(hl[2])) * w0.z + (b2f(hh[3]) + b2f(hl[3])) * w0.w +
            (b2f(hh[4]) + b2f(hl[4])) * w1.x + (b2f(hh[5]) + b2f(hl[5])) * w1.y +
            (b2f(hh[6]) + b2f(hl[6])) * w1.z + (b2f(hh[7]) + b2f(hl[7])) * w1.w;
  for (int off = 32; off > 0; off >>= 1) s += __shfl_down(s, off, 64);
  if (lane == 0) out[b] = 1.0f / (1.0f + expf(-(s + bo[0])));
}

extern "C" void kernel_launch(void* const* d_in, const int* in_sizes, int n_in,
                              void* d_out, int out_size, void* d_ws, size_t ws_size,
                              hipStream_t stream) {
  const int* tokens = (const int*)d_in[0];
  const float* emb = (const float*)d_in[1];
  const float* Wx0 = (const float*)d_in[2];
  const float* Wh0 = (const float*)d_in[3];
  const float* b0 = (const float*)d_in[4];
  const float* Wx1 = (const float*)d_in[5];
  const float* Wh1 = (const float*)d_in[6];
  const float* b1 = (const float*)d_in[7];
  const float* Wo = (const float*)d_in[8];
  const float* bo = (const float*)d_in[9];
  unsigned char* ws = (unsigned char*)d_ws;
  float* out = (float*)d_out;

  hipLaunchKernelGGL(rnn_init, dim3(1024), dim3(256), 0, stream, ws);
  hipLaunchKernelGGL(embw_gemm, dim3(V_ / 64, U_ / 64), dim3(256), 0, stream,
                     emb, Wx0, (unsigned short*)(ws + EMBW_OFF));
  hipLaunchKernelGGL(rnn_main, dim3(NC * NG), dim3(512), 0, stream, tokens,
                     b0, Wh0, Wx1, Wh1, b1, ws);
  // final h1'(127) written by L1 window w=128 at buffer (128-1)&1 == 1
  hipLaunchKernelGGL(rnn_final, dim3(256), dim3(256), 0, stream,
                     (const unsigned short*)(ws + H1H_OFF) + (size_t)1 * B_ * U_,
                     (const unsigned short*)(ws + H1L_OFF) + (size_t)1 * B_ * U_,
                     Wo, bo, out);
}

// Round 15
// 2313.043 us; speedup vs baseline: 1.1137x; 1.1137x over previous
//
#include <hip/hip_runtime.h>
#include <hip/hip_bf16.h>

#define B_ 1024
#define T_ 128
#define E_ 128
#define U_ 512
#define V_ 32000
#define NC 16   // col chunks (blocks per group)
#define NG 16   // row groups
#define MB 64   // rows per group
#define NB 32   // cols per chunk
#define HS ((size_t)B_ * U_)

#define CTR_OFF 0
#define XMASK_OFF (512u << 10)
#define FH0_OFF (520u << 10)
#define FH1_OFF (528u << 10)
#define H0H_OFF (1u << 20)   // 3 buffers x 1 MB
#define H0L_OFF (4u << 20)   // 3 buffers x 1 MB
#define H1H_OFF (7u << 20)   // 2 buffers x 1 MB
#define H1L_OFF (9u << 20)   // 2 buffers x 1 MB
#define EMBW_OFF (11u << 20)
#define ZERO_BYTES (11u << 20)

typedef unsigned int uint32;
typedef __bf16 bf16x8 __attribute__((ext_vector_type(8)));
typedef float f32x4 __attribute__((ext_vector_type(4)));
typedef unsigned short us8 __attribute__((ext_vector_type(8)));

#define MFMA __builtin_amdgcn_mfma_f32_16x16x32_bf16

__device__ __forceinline__ unsigned short f2b(float f) {
  uint32 u = __builtin_bit_cast(uint32, f);
  u += 0x7fffu + ((u >> 16) & 1u);   // RNE
  return (unsigned short)(u >> 16);
}
__device__ __forceinline__ float b2f(unsigned short h) {
  return __builtin_bit_cast(float, (uint32)h << 16);
}

// Swizzled LDS fragment read: row-major [row][K] bf16, byte ^= (row&7)<<4
__device__ __forceinline__ bf16x8 lds_frag(const unsigned short* s, int row, int k, int K) {
  uint32 off = (uint32)((row * K + k) * 2) ^ (uint32)((row & 7) << 4);
  us8 v = *(const us8*)((const char*)s + off);
  return __builtin_bit_cast(bf16x8, v);
}
__device__ __forceinline__ bf16x8 g_frag(const unsigned short* p) {
  us8 v = *(const us8*)p;
  return __builtin_bit_cast(bf16x8, v);
}
__device__ __forceinline__ void st_coh(unsigned short* p, unsigned short v) {
  __hip_atomic_store(p, v, __ATOMIC_RELAXED, __HIP_MEMORY_SCOPE_AGENT);
}
template <bool FAST>
__device__ __forceinline__ void st_h(unsigned short* p, unsigned short v) {
  if (FAST) *p = v; else st_coh(p, v);
}

// 32-entry flag poll (r14-PROVEN mechanics). Lane l polls base[l&31] >= tgt.
// FAST: plain volatile + L1 buffer_inv per retry (NEVER sc0 loads — deadlock,
// r8/r10-r12), final inv+vmcnt. SLOW: agent atomics + acquire fence.
template <bool FAST>
__device__ __forceinline__ void poll32(const uint32* base, uint32 tgt, int lane) {
  const uint32* p = base + (lane & 31);
  while (true) {
    uint32 v;
    if (FAST) v = *(const volatile uint32*)p;
    else v = __hip_atomic_load(p, __ATOMIC_RELAXED, __HIP_MEMORY_SCOPE_AGENT);
    if (__all(v >= tgt)) break;
    if (FAST) asm volatile("buffer_inv" ::: "memory");
    __builtin_amdgcn_s_sleep(2);
  }
  if (FAST) asm volatile("buffer_inv\n\ts_waitcnt vmcnt(0)" ::: "memory");
  else __builtin_amdgcn_fence(__ATOMIC_ACQUIRE, "agent");
}

// Per-wave release (r14-PROVEN): drain own stores, lane 0 publishes flag.
template <bool FAST>
__device__ __forceinline__ void signal(uint32* f, uint32 val, int lane) {
  asm volatile("s_waitcnt vmcnt(0)" ::: "memory");
  if (lane == 0) {
    if (FAST) *(volatile uint32*)f = val;
    else __hip_atomic_store(f, val, __ATOMIC_RELAXED, __HIP_MEMORY_SCOPE_AGENT);
  }
}

// Block-level group barrier (used ONCE for the XCD co-residency check).
__device__ __forceinline__ void bar_agent(uint32* ctr, int phase, int g, int tid) {
  asm volatile("s_waitcnt vmcnt(0)" ::: "memory");
  __syncthreads();
  if (tid == 0) {
    uint32* a = &ctr[(uint32)((phase << 4) | g) << 4];
    __hip_atomic_fetch_add(a, 1u, __ATOMIC_RELAXED, __HIP_MEMORY_SCOPE_AGENT);
    while (__hip_atomic_load(a, __ATOMIC_RELAXED, __HIP_MEMORY_SCOPE_AGENT) < NC)
      __builtin_amdgcn_s_sleep(1);
    __builtin_amdgcn_fence(__ATOMIC_ACQUIRE, "agent");
  }
  __syncthreads();
}

__global__ void rnn_init(unsigned char* ws) {
  const uint4 z = {0u, 0u, 0u, 0u};
  uint4* p = (uint4*)ws;
  size_t n = ZERO_BYTES / 16;
  for (size_t j = (size_t)blockIdx.x * blockDim.x + threadIdx.x; j < n;
       j += (size_t)gridDim.x * blockDim.x)
    p[j] = z;
}

// embW[v][u] = sum_e emb[v][e] * Wx0[e][u], stored bf16. grid (V/64, U/64).
__global__ __launch_bounds__(256) void embw_gemm(const float* __restrict__ emb,
                                                 const float* __restrict__ Wx0,
                                                 unsigned short* __restrict__ embW) {
  const int tid = threadIdx.x;
  const int lane = tid & 63;
  const int wv = tid >> 6;
  const int arow = lane & 15;
  const int kgrp = (lane >> 4) * 8;
  const int vrow = blockIdx.x * 64 + wv * 16;

  bf16x8 a[4];
  for (int kt = 0; kt < 4; ++kt) {
    const float* p = emb + (size_t)(vrow + arow) * E_ + kt * 32 + kgrp;
    float4 f0 = ((const float4*)p)[0];
    float4 f1 = ((const float4*)p)[1];
    us8 u;
    u[0] = f2b(f0.x); u[1] = f2b(f0.y); u[2] = f2b(f0.z); u[3] = f2b(f0.w);
    u[4] = f2b(f1.x); u[5] = f2b(f1.y); u[6] = f2b(f1.z); u[7] = f2b(f1.w);
    a[kt] = __builtin_bit_cast(bf16x8, u);
  }
  const int c0 = blockIdx.y * 64;
  for (int nt = 0; nt < 4; ++nt) {
    const int col = c0 + nt * 16 + (lane & 15);
    f32x4 acc = {0.f, 0.f, 0.f, 0.f};
    for (int kt = 0; kt < 4; ++kt) {
      us8 ub;
      for (int j = 0; j < 8; ++j)
        ub[j] = f2b(Wx0[(size_t)(kt * 32 + kgrp + j) * U_ + col]);
      acc = MFMA(a[kt], __builtin_bit_cast(bf16x8, ub), acc, 0, 0, 0);
    }
    const int crow = vrow + (lane >> 4) * 4;
    for (int i = 0; i < 4; ++i)
      embW[(size_t)(crow + i) * U_ + col] = f2b(acc[i]);
  }
}

// ---- layer-1 step at window t: h1'(t-1) = tanh(aA + h1'(t-2)@Wh1 + b1) ----
template <bool FAST>
__device__ __forceinline__ void l1_step(
    int t, f32x4 aA, unsigned short* h1h, unsigned short* h1l,
    const uint32* f1w, uint32* myF1, const unsigned short* sWh1h,
    const unsigned short* sWh1l, int r0, int c0, int lane, int colL, int rowB,
    int kgrp, int rowA, float b1v) {
  poll32<FAST>(f1w, (uint32)(t - 1), lane);  // lagged gate: usually instant
  const size_t rb1 = (size_t)(t & 1) * HS;   // h1'(t-2)
  bf16x8 ah[16], al[16];
  {
    const unsigned short* p1h = h1h + rb1 + (size_t)rowA * U_ + kgrp;
    const unsigned short* p1l = h1l + rb1 + (size_t)rowA * U_ + kgrp;
#pragma unroll
    for (int kt = 0; kt < 16; ++kt) {
      ah[kt] = g_frag(p1h + kt * 32);
      al[kt] = g_frag(p1l + kt * 32);
    }
  }
  f32x4 aB = {b1v, b1v, b1v, b1v};
#pragma unroll
  for (int kt = 0; kt < 16; ++kt) {
    bf16x8 wh = lds_frag(sWh1h, colL, kt * 32 + kgrp, U_);
    aB = MFMA(ah[kt], wh, aB, 0, 0, 0);
    aB = MFMA(al[kt], wh, aB, 0, 0, 0);
    if (kt < 15) {
      bf16x8 wl = lds_frag(sWh1l, colL, kt * 32 + kgrp, 480);
      aB = MFMA(ah[kt], wl, aB, 0, 0, 0);
    }
  }
  const size_t wb1 = (size_t)((t - 1) & 1) * HS;
  size_t ob = wb1 + (size_t)(r0 + rowB) * U_ + (c0 + colL);
  for (int i = 0; i < 4; ++i) {
    float v = tanhf(aA[i] + aB[i]);
    unsigned short hi = f2b(v);
    st_h<FAST>(&h1h[ob + (size_t)i * U_], hi);
    st_h<FAST>(&h1l[ob + (size_t)i * U_], f2b(v - b2f(hi)));
  }
  signal<FAST>(myF1, (uint32)t, lane);
}

// ---- wave-autonomous main loop: l0 first (flag early), l1 in the slack ----
template <bool FAST>
__device__ __forceinline__ void rnn_wave(
    const int* __restrict__ tokens, const unsigned short* __restrict__ embW,
    unsigned short* h0h, unsigned short* h0l, unsigned short* h1h,
    unsigned short* h1l, const uint32* f0w, const uint32* f1w, uint32* myF0,
    uint32* myF1, const unsigned short* sWh0h, const unsigned short* sWh0l,
    const unsigned short* sWx1h, const unsigned short* sWh1h,
    const unsigned short* sWh1l, int r0, int c0, int lane, int colL, int rowB,
    int kgrp, int rowA, float b0v, float b1v) {
  unsigned short embP[4];
  for (int i = 0; i < 4; ++i) {
    int tk = tokens[(size_t)(r0 + rowB + i) * T_ + 0];
    embP[i] = embW[(size_t)tk * U_ + c0 + colL];
  }

  for (int t = 0; t < T_; ++t) {
    // ===== layer 0: h0'(t) — the inter-block critical path =====
    if (t > 0) poll32<FAST>(f0w, (uint32)t, lane);
    const size_t rb0 = (size_t)((t + 2) % 3) * HS;  // h0'(t-1)
    bf16x8 hh[16], hl[16];
    {
      const unsigned short* ph = h0h + rb0 + (size_t)rowA * U_ + kgrp;
      const unsigned short* pl = h0l + rb0 + (size_t)rowA * U_ + kgrp;
#pragma unroll
      for (int kt = 0; kt < 16; ++kt) {
        hh[kt] = g_frag(ph + kt * 32);
        hl[kt] = g_frag(pl + kt * 32);
      }
    }
    f32x4 aA = {0.f, 0.f, 0.f, 0.f};
    f32x4 aC, aD = {0.f, 0.f, 0.f, 0.f};
    for (int i = 0; i < 4; ++i) aC[i] = b0v + b2f(embP[i]);
#pragma unroll
    for (int kt = 0; kt < 16; ++kt) {
      bf16x8 wx = lds_frag(sWx1h, colL, kt * 32 + kgrp, U_);
      bf16x8 wh = lds_frag(sWh0h, colL, kt * 32 + kgrp, U_);
      bf16x8 wl = lds_frag(sWh0l, colL, kt * 32 + kgrp, U_);
      aA = MFMA(hh[kt], wx, aA, 0, 0, 0);
      aA = MFMA(hl[kt], wx, aA, 0, 0, 0);
      aC = MFMA(hh[kt], wh, aC, 0, 0, 0);
      aD = MFMA(hl[kt], wh, aD, 0, 0, 0);
      aD = MFMA(hh[kt], wl, aD, 0, 0, 0);
    }
    {
      const size_t wb = (size_t)(t % 3) * HS;
      size_t ob = wb + (size_t)(r0 + rowB) * U_ + (c0 + colL);
      for (int i = 0; i < 4; ++i) {
        float v = tanhf(aC[i] + aD[i]);
        unsigned short hi = f2b(v);
        st_h<FAST>(&h0h[ob + (size_t)i * U_], hi);
        st_h<FAST>(&h0l[ob + (size_t)i * U_], f2b(v - b2f(hi)));
      }
    }
    signal<FAST>(myF0, (uint32)(t + 1), lane);  // release ASAP

    // embW gather for t+1 — strictly after the release (off critical path)
    if (t + 1 < T_) {
      for (int i = 0; i < 4; ++i) {
        int tk = tokens[(size_t)(r0 + rowB + i) * T_ + (t + 1)];
        embP[i] = embW[(size_t)tk * U_ + c0 + colL];
      }
    }

    // ===== layer 1 (lagged): h1'(t-1) — runs in the slack =====
    if (t >= 1)
      l1_step<FAST>(t, aA, h1h, h1l, f1w, myF1, sWh1h, sWh1l, r0, c0, lane,
                    colL, rowB, kgrp, rowA, b1v);
  }

  // ===== epilogue: h1'(T-1) needs aA from h0'(T-1) =====
  {
    poll32<FAST>(f0w, (uint32)T_, lane);
    const size_t rb0 = (size_t)((T_ + 2) % 3) * HS;
    bf16x8 hh[16], hl[16];
    {
      const unsigned short* ph = h0h + rb0 + (size_t)rowA * U_ + kgrp;
      const unsigned short* pl = h0l + rb0 + (size_t)rowA * U_ + kgrp;
#pragma unroll
      for (int kt = 0; kt < 16; ++kt) {
        hh[kt] = g_frag(ph + kt * 32);
        hl[kt] = g_frag(pl + kt * 32);
      }
    }
    f32x4 aA = {0.f, 0.f, 0.f, 0.f};
#pragma unroll
    for (int kt = 0; kt < 16; ++kt) {
      bf16x8 wx = lds_frag(sWx1h, colL, kt * 32 + kgrp, U_);
      aA = MFMA(hh[kt], wx, aA, 0, 0, 0);
      aA = MFMA(hl[kt], wx, aA, 0, 0, 0);
    }
    l1_step<FAST>(T_, aA, h1h, h1l, f1w, myF1, sWh1h, sWh1l, r0, c0, lane,
                  colL, rowB, kgrp, rowA, b1v);
  }
}

__global__ __launch_bounds__(512, 2) void rnn_main(
    const int* __restrict__ tokens, const float* __restrict__ b0,
    const float* __restrict__ Wh0, const float* __restrict__ Wx1,
    const float* __restrict__ Wh1, const float* __restrict__ b1,
    unsigned char* ws) {
  __shared__ unsigned short sWh0h[NB * U_];   // 32 KB
  __shared__ unsigned short sWh0l[NB * U_];   // 32 KB
  __shared__ unsigned short sWx1h[NB * U_];   // 32 KB
  __shared__ unsigned short sWh1h[NB * U_];   // 32 KB
  __shared__ unsigned short sWh1l[NB * 480];  // 30 KB
  __shared__ uint32 sFast;

  const int tid = threadIdx.x;
  const int bid = blockIdx.x;
  const int g = bid & (NG - 1);
  const int c = bid >> 4;
  const int r0 = g * MB;
  const int c0 = c * NB;

  uint32* ctr = (uint32*)(ws + CTR_OFF);
  uint32* fH0 = (uint32*)(ws + FH0_OFF);
  uint32* fH1 = (uint32*)(ws + FH1_OFF);
  unsigned short* h0h = (unsigned short*)(ws + H0H_OFF);
  unsigned short* h0l = (unsigned short*)(ws + H0L_OFF);
  unsigned short* h1h = (unsigned short*)(ws + H1H_OFF);
  unsigned short* h1l = (unsigned short*)(ws + H1L_OFF);
  const unsigned short* embW = (const unsigned short*)(ws + EMBW_OFF);

  // ---- stage weight slices: f32 global -> bf16 hi(+lo) swizzled LDS ----
  for (int idx = tid; idx < NB * U_; idx += 512) {
    int cl = idx & 31, k = idx >> 5;
    float v = Wh0[(size_t)k * U_ + c0 + cl];
    unsigned short hi = f2b(v);
    uint32 off = (uint32)((cl * U_ + k) * 2) ^ (uint32)((cl & 7) << 4);
    *(unsigned short*)((char*)sWh0h + off) = hi;
    *(unsigned short*)((char*)sWh0l + off) = f2b(v - b2f(hi));
  }
  for (int idx = tid; idx < NB * U_; idx += 512) {
    int cl = idx & 31, k = idx >> 5;
    float v = Wx1[(size_t)k * U_ + c0 + cl];
    uint32 off = (uint32)((cl * U_ + k) * 2) ^ (uint32)((cl & 7) << 4);
    *(unsigned short*)((char*)sWx1h + off) = f2b(v);
  }
  for (int idx = tid; idx < NB * U_; idx += 512) {
    int cl = idx & 31, k = idx >> 5;
    float v = Wh1[(size_t)k * U_ + c0 + cl];
    unsigned short hi = f2b(v);
    uint32 off = (uint32)((cl * U_ + k) * 2) ^ (uint32)((cl & 7) << 4);
    *(unsigned short*)((char*)sWh1h + off) = hi;
    if (k < 480) {
      uint32 offl = (uint32)((cl * 480 + k) * 2) ^ (uint32)((cl & 7) << 4);
      *(unsigned short*)((char*)sWh1l + offl) = f2b(v - b2f(hi));
    }
  }

  // ---- runtime XCD co-residency check (G16: never ASSUME the mapping) ----
  {
    uint32 xcd;
    asm volatile("s_getreg_b32 %0, hwreg(HW_REG_XCC_ID)" : "=s"(xcd));
    uint32* xm = (uint32*)(ws + XMASK_OFF) + (uint32)g * 16;
    if (tid == 0)
      __hip_atomic_fetch_or(xm, 1u << (xcd & 31u), __ATOMIC_RELAXED,
                            __HIP_MEMORY_SCOPE_AGENT);
    bar_agent(ctr, T_, g, tid);
    if (tid == 0) {
      uint32 m = __hip_atomic_load(xm, __ATOMIC_RELAXED, __HIP_MEMORY_SCOPE_AGENT);
      sFast = (__popc(m) == 1) ? 1u : 0u;
    }
  }

  const int lane = tid & 63;
  const int wv = tid >> 6;       // 8 waves = 4 mt x 2 nt
  const int mt = wv & 3;
  const int nt = wv >> 2;
  const int l15 = lane & 15;
  const int colL = nt * 16 + l15;
  const int rowB = mt * 16 + ((lane >> 4) << 2);
  const int kgrp = (lane >> 4) * 8;
  const int rowA = r0 + mt * 16 + l15;
  const float b0v = b0[c0 + colL];
  const float b1v = b1[c0 + colL];

  // flags: [g][mt][peer c][nt] -> 32 words per (g,mt)
  const uint32* f0w = fH0 + ((uint32)(g * 4 + mt) * 32);
  const uint32* f1w = fH1 + ((uint32)(g * 4 + mt) * 32);
  uint32* myF0 = (uint32*)f0w + (c * 2 + nt);
  uint32* myF1 = (uint32*)f1w + (c * 2 + nt);

  __syncthreads();  // weights staged + sFast visible; waves autonomous after
  const bool fast = (sFast != 0);

  if (fast)
    rnn_wave<true>(tokens, embW, h0h, h0l, h1h, h1l, f0w, f1w, myF0, myF1,
                   sWh0h, sWh0l, sWx1h, sWh1h, sWh1l, r0, c0, lane, colL,
                   rowB, kgrp, rowA, b0v, b1v);
  else
    rnn_wave<false>(tokens, embW, h0h, h0l, h1h, h1l, f0w, f1w, myF0, myF1,
                    sWh0h, sWh0l, sWx1h, sWh1h, sWh1l, r0, c0, lane, colL,
                    rowB, kgrp, rowA, b0v, b1v);
}

__global__ void rnn_final(const unsigned short* __restrict__ h1h,
                          const unsigned short* __restrict__ h1l,
                          const float* __restrict__ Wo,
                          const float* __restrict__ bo, float* __restrict__ out) {
  int lane = threadIdx.x & 63;
  int b = blockIdx.x * 4 + (threadIdx.x >> 6);
  us8 hh = *(const us8*)(h1h + (size_t)b * U_ + lane * 8);
  us8 hl = *(const us8*)(h1l + (size_t)b * U_ + lane * 8);
  const float4* wp = (const float4*)(Wo + lane * 8);
  float4 w0 = wp[0], w1 = wp[1];
  float s = (b2f(hh[0]) + b2f(hl[0])) * w0.x + (b2f(hh[1]) + b2f(hl[1])) * w0.y +
            (b2f(hh[2]) + b2f(hl[2])) * w0.z + (b2f(hh[3]) + b2f(hl[3])) * w0.w +
            (b2f(hh[4]) + b2f(hl[4])) * w1.x + (b2f(hh[5]) + b2f(hl[5])) * w1.y +
            (b2f(hh[6]) + b2f(hl[6])) * w1.z + (b2f(hh[7]) + b2f(hl[7])) * w1.w;
  for (int off = 32; off > 0; off >>= 1) s += __shfl_down(s, off, 64);
  if (lane == 0) out[b] = 1.0f / (1.0f + expf(-(s + bo[0])));
}

extern "C" void kernel_launch(void* const* d_in, const int* in_sizes, int n_in,
                              void* d_out, int out_size, void* d_ws, size_t ws_size,
                              hipStream_t stream) {
  const int* tokens = (const int*)d_in[0];
  const float* emb = (const float*)d_in[1];
  const float* Wx0 = (const float*)d_in[2];
  const float* Wh0 = (const float*)d_in[3];
  const float* b0 = (const float*)d_in[4];
  const float* Wx1 = (const float*)d_in[5];
  const float* Wh1 = (const float*)d_in[6];
  const float* b1 = (const float*)d_in[7];
  const float* Wo = (const float*)d_in[8];
  const float* bo = (const float*)d_in[9];
  unsigned char* ws = (unsigned char*)d_ws;
  float* out = (float*)d_out;

  hipLaunchKernelGGL(rnn_init, dim3(1024), dim3(256), 0, stream, ws);
  hipLaunchKernelGGL(embw_gemm, dim3(V_ / 64, U_ / 64), dim3(256), 0, stream,
                     emb, Wx0, (unsigned short*)(ws + EMBW_OFF));
  hipLaunchKernelGGL(rnn_main, dim3(NC * NG), dim3(512), 0, stream, tokens,
                     b0, Wh0, Wx1, Wh1, b1, ws);
  // final h1'(T-1) written by the epilogue at buffer (T_-1)&1 == 1
  hipLaunchKernelGGL(rnn_final, dim3(256), dim3(256), 0, stream,
                     (const unsigned short*)(ws + H1H_OFF) + (size_t)1 * B_ * U_,
                     (const unsigned short*)(ws + H1L_OFF) + (size_t)1 * B_ * U_,
                     Wo, bo, out);
}

// Round 16
// 2294.720 us; speedup vs baseline: 1.1226x; 1.0080x over previous
//
#include <hip/hip_runtime.h>
#include <hip/hip_bf16.h>

#define B_ 1024
#define T_ 128
#define E_ 128
#define U_ 512
#define V_ 32000
#define NC 16   // col chunks (blocks per group)
#define NG 16   // row groups
#define MB 64   // rows per group
#define NB 32   // cols per chunk
#define HS ((size_t)B_ * U_)

#define CTR_OFF 0
#define XMASK_OFF (512u << 10)
#define FH0_OFF (520u << 10)
#define FH1_OFF (528u << 10)
#define H0H_OFF (1u << 20)   // 3 buffers x 1 MB
#define H0L_OFF (4u << 20)   // 3 buffers x 1 MB
#define H1H_OFF (7u << 20)   // 2 buffers x 1 MB
#define H1L_OFF (9u << 20)   // 2 buffers x 1 MB
#define EMBW_OFF (11u << 20)
#define ZERO_BYTES (11u << 20)

typedef unsigned int uint32;
typedef __bf16 bf16x8 __attribute__((ext_vector_type(8)));
typedef float f32x4 __attribute__((ext_vector_type(4)));
typedef unsigned short us8 __attribute__((ext_vector_type(8)));

#define MFMA __builtin_amdgcn_mfma_f32_16x16x32_bf16

__device__ __forceinline__ unsigned short f2b(float f) {
  uint32 u = __builtin_bit_cast(uint32, f);
  u += 0x7fffu + ((u >> 16) & 1u);   // RNE
  return (unsigned short)(u >> 16);
}
__device__ __forceinline__ float b2f(unsigned short h) {
  return __builtin_bit_cast(float, (uint32)h << 16);
}

// Swizzled LDS fragment read: row-major [row][K] bf16, byte ^= (row&7)<<4
__device__ __forceinline__ bf16x8 lds_frag(const unsigned short* s, int row, int k, int K) {
  uint32 off = (uint32)((row * K + k) * 2) ^ (uint32)((row & 7) << 4);
  us8 v = *(const us8*)((const char*)s + off);
  return __builtin_bit_cast(bf16x8, v);
}
__device__ __forceinline__ bf16x8 g_frag(const unsigned short* p) {
  us8 v = *(const us8*)p;
  return __builtin_bit_cast(bf16x8, v);
}
__device__ __forceinline__ void st_coh(unsigned short* p, unsigned short v) {
  __hip_atomic_store(p, v, __ATOMIC_RELAXED, __HIP_MEMORY_SCOPE_AGENT);
}
template <bool FAST>
__device__ __forceinline__ void st_h(unsigned short* p, unsigned short v) {
  if (FAST) *p = v; else st_coh(p, v);
}

// 32-entry flag poll (r14/r15-PROVEN mechanics). Lane l polls base[l&31] >= tgt.
// FAST: plain volatile + L1 buffer_inv per retry (NEVER sc0 loads — unreliable,
// r8/r10-r12 hangs), final inv+vmcnt. SLOW: agent atomics + acquire fence.
template <bool FAST>
__device__ __forceinline__ void poll32(const uint32* base, uint32 tgt, int lane) {
  const uint32* p = base + (lane & 31);
  while (true) {
    uint32 v;
    if (FAST) v = *(const volatile uint32*)p;
    else v = __hip_atomic_load(p, __ATOMIC_RELAXED, __HIP_MEMORY_SCOPE_AGENT);
    if (__all(v >= tgt)) break;
    if (FAST) asm volatile("buffer_inv" ::: "memory");
    __builtin_amdgcn_s_sleep(2);
  }
  if (FAST) asm volatile("buffer_inv\n\ts_waitcnt vmcnt(0)" ::: "memory");
  else __builtin_amdgcn_fence(__ATOMIC_ACQUIRE, "agent");
}

// Per-wave release (r14-PROVEN): drain own stores, lane 0 publishes flag.
template <bool FAST>
__device__ __forceinline__ void signal(uint32* f, uint32 val, int lane) {
  asm volatile("s_waitcnt vmcnt(0)" ::: "memory");
  if (lane == 0) {
    if (FAST) *(volatile uint32*)f = val;
    else __hip_atomic_store(f, val, __ATOMIC_RELAXED, __HIP_MEMORY_SCOPE_AGENT);
  }
}

// Block-level group barrier (used ONCE for the XCD co-residency check).
__device__ __forceinline__ void bar_agent(uint32* ctr, int phase, int g, int tid) {
  asm volatile("s_waitcnt vmcnt(0)" ::: "memory");
  __syncthreads();
  if (tid == 0) {
    uint32* a = &ctr[(uint32)((phase << 4) | g) << 4];
    __hip_atomic_fetch_add(a, 1u, __ATOMIC_RELAXED, __HIP_MEMORY_SCOPE_AGENT);
    while (__hip_atomic_load(a, __ATOMIC_RELAXED, __HIP_MEMORY_SCOPE_AGENT) < NC)
      __builtin_amdgcn_s_sleep(1);
    __builtin_amdgcn_fence(__ATOMIC_ACQUIRE, "agent");
  }
  __syncthreads();
}

__global__ void rnn_init(unsigned char* ws) {
  const uint4 z = {0u, 0u, 0u, 0u};
  uint4* p = (uint4*)ws;
  size_t n = ZERO_BYTES / 16;
  for (size_t j = (size_t)blockIdx.x * blockDim.x + threadIdx.x; j < n;
       j += (size_t)gridDim.x * blockDim.x)
    p[j] = z;
}

// embW[v][u] = sum_e emb[v][e] * Wx0[e][u], stored bf16. grid (V/64, U/64).
__global__ __launch_bounds__(256) void embw_gemm(const float* __restrict__ emb,
                                                 const float* __restrict__ Wx0,
                                                 unsigned short* __restrict__ embW) {
  const int tid = threadIdx.x;
  const int lane = tid & 63;
  const int wv = tid >> 6;
  const int arow = lane & 15;
  const int kgrp = (lane >> 4) * 8;
  const int vrow = blockIdx.x * 64 + wv * 16;

  bf16x8 a[4];
  for (int kt = 0; kt < 4; ++kt) {
    const float* p = emb + (size_t)(vrow + arow) * E_ + kt * 32 + kgrp;
    float4 f0 = ((const float4*)p)[0];
    float4 f1 = ((const float4*)p)[1];
    us8 u;
    u[0] = f2b(f0.x); u[1] = f2b(f0.y); u[2] = f2b(f0.z); u[3] = f2b(f0.w);
    u[4] = f2b(f1.x); u[5] = f2b(f1.y); u[6] = f2b(f1.z); u[7] = f2b(f1.w);
    a[kt] = __builtin_bit_cast(bf16x8, u);
  }
  const int c0 = blockIdx.y * 64;
  for (int nt = 0; nt < 4; ++nt) {
    const int col = c0 + nt * 16 + (lane & 15);
    f32x4 acc = {0.f, 0.f, 0.f, 0.f};
    for (int kt = 0; kt < 4; ++kt) {
      us8 ub;
      for (int j = 0; j < 8; ++j)
        ub[j] = f2b(Wx0[(size_t)(kt * 32 + kgrp + j) * U_ + col]);
      acc = MFMA(a[kt], __builtin_bit_cast(bf16x8, ub), acc, 0, 0, 0);
    }
    const int crow = vrow + (lane >> 4) * 4;
    for (int i = 0; i < 4; ++i)
      embW[(size_t)(crow + i) * U_ + col] = f2b(acc[i]);
  }
}

// ---- layer-1 step at window t: h1'(t-1) = tanh(aA + h1'(t-2)@Wh1 + b1) ----
template <bool FAST>
__device__ __forceinline__ void l1_step(
    int t, f32x4 aA, unsigned short* h1h, unsigned short* h1l,
    const uint32* f1w, uint32* myF1, const unsigned short* sWh1h,
    const unsigned short* sWh1l, int r0, int c0, int lane, int colL, int rowB,
    int kgrp, int rowA, float b1v) {
  poll32<FAST>(f1w, (uint32)(t - 1), lane);  // lagged gate: usually instant
  const size_t rb1 = (size_t)(t & 1) * HS;   // h1'(t-2)
  bf16x8 ah[16], al[16];
  {
    const unsigned short* p1h = h1h + rb1 + (size_t)rowA * U_ + kgrp;
    const unsigned short* p1l = h1l + rb1 + (size_t)rowA * U_ + kgrp;
#pragma unroll
    for (int kt = 0; kt < 16; ++kt) {
      ah[kt] = g_frag(p1h + kt * 32);
      al[kt] = g_frag(p1l + kt * 32);
    }
  }
  f32x4 aB = {b1v, b1v, b1v, b1v};
#pragma unroll
  for (int kt = 0; kt < 16; ++kt) {
    bf16x8 wh = lds_frag(sWh1h, colL, kt * 32 + kgrp, U_);
    aB = MFMA(ah[kt], wh, aB, 0, 0, 0);
    aB = MFMA(al[kt], wh, aB, 0, 0, 0);
    if (kt < 15) {
      bf16x8 wl = lds_frag(sWh1l, colL, kt * 32 + kgrp, 480);
      aB = MFMA(ah[kt], wl, aB, 0, 0, 0);
    }
  }
  const size_t wb1 = (size_t)((t - 1) & 1) * HS;
  size_t ob = wb1 + (size_t)(r0 + rowB) * U_ + (c0 + colL);
  for (int i = 0; i < 4; ++i) {
    float v = tanhf(aA[i] + aB[i]);
    unsigned short hi = f2b(v);
    st_h<FAST>(&h1h[ob + (size_t)i * U_], hi);
    st_h<FAST>(&h1l[ob + (size_t)i * U_], f2b(v - b2f(hi)));
  }
  signal<FAST>(myF1, (uint32)t, lane);
}

// ---- wave-autonomous main loop: l0 first (flag early), l1 in the slack ----
template <bool FAST>
__device__ __forceinline__ void rnn_wave(
    const int* __restrict__ tokens, const unsigned short* __restrict__ embW,
    unsigned short* h0h, unsigned short* h0l, unsigned short* h1h,
    unsigned short* h1l, const uint32* f0w, const uint32* f1w, uint32* myF0,
    uint32* myF1, const unsigned short* sWh0h, const unsigned short* sWh0l,
    const unsigned short* sWx1h, const unsigned short* sWh1h,
    const unsigned short* sWh1l, int r0, int c0, int lane, int colL, int rowB,
    int kgrp, int rowA, float b0v, float b1v) {
  unsigned short embP[4];
  for (int i = 0; i < 4; ++i) {
    int tk = tokens[(size_t)(r0 + rowB + i) * T_ + 0];
    embP[i] = embW[(size_t)tk * U_ + c0 + colL];
  }

  for (int t = 0; t < T_; ++t) {
    // ===== layer 0: h0'(t) — the inter-block critical path =====
    if (t > 0) poll32<FAST>(f0w, (uint32)t, lane);
    const size_t rb0 = (size_t)((t + 2) % 3) * HS;  // h0'(t-1)
    bf16x8 hh[16], hl[16];
    {
      const unsigned short* ph = h0h + rb0 + (size_t)rowA * U_ + kgrp;
      const unsigned short* pl = h0l + rb0 + (size_t)rowA * U_ + kgrp;
#pragma unroll
      for (int kt = 0; kt < 16; ++kt) {
        hh[kt] = g_frag(ph + kt * 32);
        hl[kt] = g_frag(pl + kt * 32);
      }
    }
    f32x4 aA = {0.f, 0.f, 0.f, 0.f};
    f32x4 aC, aD = {0.f, 0.f, 0.f, 0.f};
    for (int i = 0; i < 4; ++i) aC[i] = b0v + b2f(embP[i]);
#pragma unroll
    for (int kt = 0; kt < 16; ++kt) {
      bf16x8 wx = lds_frag(sWx1h, colL, kt * 32 + kgrp, U_);
      bf16x8 wh = lds_frag(sWh0h, colL, kt * 32 + kgrp, U_);
      bf16x8 wl = lds_frag(sWh0l, colL, kt * 32 + kgrp, U_);
      aA = MFMA(hh[kt], wx, aA, 0, 0, 0);
      aA = MFMA(hl[kt], wx, aA, 0, 0, 0);
      aC = MFMA(hh[kt], wh, aC, 0, 0, 0);
      aD = MFMA(hl[kt], wh, aD, 0, 0, 0);
      aD = MFMA(hh[kt], wl, aD, 0, 0, 0);
    }
    {
      const size_t wb = (size_t)(t % 3) * HS;
      size_t ob = wb + (size_t)(r0 + rowB) * U_ + (c0 + colL);
      for (int i = 0; i < 4; ++i) {
        float v = tanhf(aC[i] + aD[i]);
        unsigned short hi = f2b(v);
        st_h<FAST>(&h0h[ob + (size_t)i * U_], hi);
        st_h<FAST>(&h0l[ob + (size_t)i * U_], f2b(v - b2f(hi)));
      }
    }
    signal<FAST>(myF0, (uint32)(t + 1), lane);  // release ASAP

    // embW gather for t+1 — strictly after the release (off critical path)
    if (t + 1 < T_) {
      for (int i = 0; i < 4; ++i) {
        int tk = tokens[(size_t)(r0 + rowB + i) * T_ + (t + 1)];
        embP[i] = embW[(size_t)tk * U_ + c0 + colL];
      }
    }

    // ===== layer 1 (lagged): h1'(t-1) — runs in the slack =====
    if (t >= 1)
      l1_step<FAST>(t, aA, h1h, h1l, f1w, myF1, sWh1h, sWh1l, r0, c0, lane,
                    colL, rowB, kgrp, rowA, b1v);
  }

  // ===== epilogue: h1'(T-1) needs aA from h0'(T-1) =====
  {
    poll32<FAST>(f0w, (uint32)T_, lane);
    const size_t rb0 = (size_t)((T_ + 2) % 3) * HS;
    bf16x8 hh[16], hl[16];
    {
      const unsigned short* ph = h0h + rb0 + (size_t)rowA * U_ + kgrp;
      const unsigned short* pl = h0l + rb0 + (size_t)rowA * U_ + kgrp;
#pragma unroll
      for (int kt = 0; kt < 16; ++kt) {
        hh[kt] = g_frag(ph + kt * 32);
        hl[kt] = g_frag(pl + kt * 32);
      }
    }
    f32x4 aA = {0.f, 0.f, 0.f, 0.f};
#pragma unroll
    for (int kt = 0; kt < 16; ++kt) {
      bf16x8 wx = lds_frag(sWx1h, colL, kt * 32 + kgrp, U_);
      aA = MFMA(hh[kt], wx, aA, 0, 0, 0);
      aA = MFMA(hl[kt], wx, aA, 0, 0, 0);
    }
    l1_step<FAST>(T_, aA, h1h, h1l, f1w, myF1, sWh1h, sWh1l, r0, c0, lane,
                  colL, rowB, kgrp, rowA, b1v);
  }
}

// Exactly 512 threads, exactly 2 waves/EU (LDS caps the CU at one block
// anyway) -> compiler may use the full 256-VGPR budget and keep the 128-reg
// fragment batches LIVE (batched L2 loads) instead of rematerializing in
// 4-load chunks (r15: VGPR_Count=128, ~8 exposed L2 round-trips per phase).
__global__ __attribute__((amdgpu_flat_work_group_size(512, 512),
                          amdgpu_waves_per_eu(2, 2))) void rnn_main(
    const int* __restrict__ tokens, const float* __restrict__ b0,
    const float* __restrict__ Wh0, const float* __restrict__ Wx1,
    const float* __restrict__ Wh1, const float* __restrict__ b1,
    unsigned char* ws) {
  __shared__ unsigned short sWh0h[NB * U_];   // 32 KB
  __shared__ unsigned short sWh0l[NB * U_];   // 32 KB
  __shared__ unsigned short sWx1h[NB * U_];   // 32 KB
  __shared__ unsigned short sWh1h[NB * U_];   // 32 KB
  __shared__ unsigned short sWh1l[NB * 480];  // 30 KB
  __shared__ uint32 sFast;

  const int tid = threadIdx.x;
  const int bid = blockIdx.x;
  const int g = bid & (NG - 1);
  const int c = bid >> 4;
  const int r0 = g * MB;
  const int c0 = c * NB;

  uint32* ctr = (uint32*)(ws + CTR_OFF);
  uint32* fH0 = (uint32*)(ws + FH0_OFF);
  uint32* fH1 = (uint32*)(ws + FH1_OFF);
  unsigned short* h0h = (unsigned short*)(ws + H0H_OFF);
  unsigned short* h0l = (unsigned short*)(ws + H0L_OFF);
  unsigned short* h1h = (unsigned short*)(ws + H1H_OFF);
  unsigned short* h1l = (unsigned short*)(ws + H1L_OFF);
  const unsigned short* embW = (const unsigned short*)(ws + EMBW_OFF);

  // ---- stage weight slices: f32 global -> bf16 hi(+lo) swizzled LDS ----
  for (int idx = tid; idx < NB * U_; idx += 512) {
    int cl = idx & 31, k = idx >> 5;
    float v = Wh0[(size_t)k * U_ + c0 + cl];
    unsigned short hi = f2b(v);
    uint32 off = (uint32)((cl * U_ + k) * 2) ^ (uint32)((cl & 7) << 4);
    *(unsigned short*)((char*)sWh0h + off) = hi;
    *(unsigned short*)((char*)sWh0l + off) = f2b(v - b2f(hi));
  }
  for (int idx = tid; idx < NB * U_; idx += 512) {
    int cl = idx & 31, k = idx >> 5;
    float v = Wx1[(size_t)k * U_ + c0 + cl];
    uint32 off = (uint32)((cl * U_ + k) * 2) ^ (uint32)((cl & 7) << 4);
    *(unsigned short*)((char*)sWx1h + off) = f2b(v);
  }
  for (int idx = tid; idx < NB * U_; idx += 512) {
    int cl = idx & 31, k = idx >> 5;
    float v = Wh1[(size_t)k * U_ + c0 + cl];
    unsigned short hi = f2b(v);
    uint32 off = (uint32)((cl * U_ + k) * 2) ^ (uint32)((cl & 7) << 4);
    *(unsigned short*)((char*)sWh1h + off) = hi;
    if (k < 480) {
      uint32 offl = (uint32)((cl * 480 + k) * 2) ^ (uint32)((cl & 7) << 4);
      *(unsigned short*)((char*)sWh1l + offl) = f2b(v - b2f(hi));
    }
  }

  // ---- runtime XCD co-residency check (G16: never ASSUME the mapping) ----
  {
    uint32 xcd;
    asm volatile("s_getreg_b32 %0, hwreg(HW_REG_XCC_ID)" : "=s"(xcd));
    uint32* xm = (uint32*)(ws + XMASK_OFF) + (uint32)g * 16;
    if (tid == 0)
      __hip_atomic_fetch_or(xm, 1u << (xcd & 31u), __ATOMIC_RELAXED,
                            __HIP_MEMORY_SCOPE_AGENT);
    bar_agent(ctr, T_, g, tid);
    if (tid == 0) {
      uint32 m = __hip_atomic_load(xm, __ATOMIC_RELAXED, __HIP_MEMORY_SCOPE_AGENT);
      sFast = (__popc(m) == 1) ? 1u : 0u;
    }
  }

  const int lane = tid & 63;
  const int wv = tid >> 6;       // 8 waves = 4 mt x 2 nt
  const int mt = wv & 3;
  const int nt = wv >> 2;
  const int l15 = lane & 15;
  const int colL = nt * 16 + l15;
  const int rowB = mt * 16 + ((lane >> 4) << 2);
  const int kgrp = (lane >> 4) * 8;
  const int rowA = r0 + mt * 16 + l15;
  const float b0v = b0[c0 + colL];
  const float b1v = b1[c0 + colL];

  // flags: [g][mt][peer c][nt] -> 32 words per (g,mt)
  const uint32* f0w = fH0 + ((uint32)(g * 4 + mt) * 32);
  const uint32* f1w = fH1 + ((uint32)(g * 4 + mt) * 32);
  uint32* myF0 = (uint32*)f0w + (c * 2 + nt);
  uint32* myF1 = (uint32*)f1w + (c * 2 + nt);

  __syncthreads();  // weights staged + sFast visible; waves autonomous after
  const bool fast = (sFast != 0);

  if (fast)
    rnn_wave<true>(tokens, embW, h0h, h0l, h1h, h1l, f0w, f1w, myF0, myF1,
                   sWh0h, sWh0l, sWx1h, sWh1h, sWh1l, r0, c0, lane, colL,
                   rowB, kgrp, rowA, b0v, b1v);
  else
    rnn_wave<false>(tokens, embW, h0h, h0l, h1h, h1l, f0w, f1w, myF0, myF1,
                    sWh0h, sWh0l, sWx1h, sWh1h, sWh1l, r0, c0, lane, colL,
                    rowB, kgrp, rowA, b0v, b1v);
}

__global__ void rnn_final(const unsigned short* __restrict__ h1h,
                          const unsigned short* __restrict__ h1l,
                          const float* __restrict__ Wo,
                          const float* __restrict__ bo, float* __restrict__ out) {
  int lane = threadIdx.x & 63;
  int b = blockIdx.x * 4 + (threadIdx.x >> 6);
  us8 hh = *(const us8*)(h1h + (size_t)b * U_ + lane * 8);
  us8 hl = *(const us8*)(h1l + (size_t)b * U_ + lane * 8);
  const float4* wp = (const float4*)(Wo + lane * 8);
  float4 w0 = wp[0], w1 = wp[1];
  float s = (b2f(hh[0]) + b2f(hl[0])) * w0.x + (b2f(hh[1]) + b2f(hl[1])) * w0.y +
            (b2f(hh[2]) + b2f(hl[2])) * w0.z + (b2f(hh[3]) + b2f(hl[3])) * w0.w +
            (b2f(hh[4]) + b2f(hl[4])) * w1.x + (b2f(hh[5]) + b2f(hl[5])) * w1.y +
            (b2f(hh[6]) + b2f(hl[6])) * w1.z + (b2f(hh[7]) + b2f(hl[7])) * w1.w;
  for (int off = 32; off > 0; off >>= 1) s += __shfl_down(s, off, 64);
  if (lane == 0) out[b] = 1.0f / (1.0f + expf(-(s + bo[0])));
}

extern "C" void kernel_launch(void* const* d_in, const int* in_sizes, int n_in,
                              void* d_out, int out_size, void* d_ws, size_t ws_size,
                              hipStream_t stream) {
  const int* tokens = (const int*)d_in[0];
  const float* emb = (const float*)d_in[1];
  const float* Wx0 = (const float*)d_in[2];
  const float* Wh0 = (const float*)d_in[3];
  const float* b0 = (const float*)d_in[4];
  const float* Wx1 = (const float*)d_in[5];
  const float* Wh1 = (const float*)d_in[6];
  const float* b1 = (const float*)d_in[7];
  const float* Wo = (const float*)d_in[8];
  const float* bo = (const float*)d_in[9];
  unsigned char* ws = (unsigned char*)d_ws;
  float* out = (float*)d_out;

  hipLaunchKernelGGL(rnn_init, dim3(1024), dim3(256), 0, stream, ws);
  hipLaunchKernelGGL(embw_gemm, dim3(V_ / 64, U_ / 64), dim3(256), 0, stream,
                     emb, Wx0, (unsigned short*)(ws + EMBW_OFF));
  hipLaunchKernelGGL(rnn_main, dim3(NC * NG), dim3(512), 0, stream, tokens,
                     b0, Wh0, Wx1, Wh1, b1, ws);
  // final h1'(T-1) written by the epilogue at buffer (T_-1)&1 == 1
  hipLaunchKernelGGL(rnn_final, dim3(256), dim3(256), 0, stream,
                     (const unsigned short*)(ws + H1H_OFF) + (size_t)1 * B_ * U_,
                     (const unsigned short*)(ws + H1L_OFF) + (size_t)1 * B_ * U_,
                     Wo, bo, out);
}